// Round 9
// baseline (1700.425 us; speedup 1.0000x reference)
//
#include <hip/hip_runtime.h>

constexpr int Bc = 8, Nc = 4096, Dc = 256, Hc = 8;
constexpr int TN = 32;    // rows per workgroup in GEMM kernels
constexpr int XS = 36;    // padded LDS stride

// ---------------- K1: head GEMM + lsh/simv + down GEMM (fused) ----------------
__global__ __launch_bounds__(256, 2)
void k1_head_down(const float* __restrict__ x,
                  const float* __restrict__ Wh, const float* __restrict__ bh,
                  const float* __restrict__ Wd, const float* __restrict__ bd,
                  float* __restrict__ z, float* __restrict__ simv)
{
    __shared__ float xT[256 * XS];   // xT[k*XS + r] = x[row r][k]; tail reused as vals scatter
    __shared__ float qT[256 * XS];   // per-h q transposed; reused as int lsh later
    __shared__ float pe_over[256];   // pe(pos=d) / 0.4f  (XLA:CPU libm-CR model)
    __shared__ float c_f[256];       // 0.4f * 0.6f^j (HloEvaluator const-fold, CR powf)
    __shared__ int   cnt_l[TN * 16];

    const int tid = threadIdx.x;
    const long rowbase = (long)blockIdx.x * TN;

    {
        // ---- XLA:CPU table model: llvm.pow/sin/cos.f32 -> glibc CR -> f64-round ----
        const int d = tid;
        const float u = -((float)d * 0.00390625f);        // -(d/256), exact
        const float freq = (float)pow(10.0, (double)u);   // CR powf model (no algsimp rewrite)
        const float pe = (d & 1) ? (float)sin((double)freq)
                                 : (float)cos((double)freq);
        pe_over[d] = __fdiv_rn(pe, 0.4f);                 // f32 division, CR
        c_f[d] = __fmul_rn(0.4f, (float)pow((double)0.6f, (double)d));
    }
    #pragma unroll
    for (int r = 0; r < TN; ++r)
        xT[tid * XS + r] = x[(rowbase + r) * 256 + tid];

    float accz[TN];
    int   lshv[TN];
    #pragma unroll
    for (int r = 0; r < TN; ++r) { accz[r] = 0.0f; lshv[r] = 0; }

    __syncthreads();

    for (int h = 0; h < Hc; ++h) {
        float accq[TN];
        #pragma unroll
        for (int r = 0; r < TN; ++r) accq[r] = 0.0f;
        const float* wc = Wh + h * 256 + tid;      // head_kernel[d=k][h][e=tid], stride 2048
        // Eigen gebp model: per output element single ascending-k FMA chain (K=256 unblocked)
        #pragma unroll 2
        for (int k = 0; k < 256; ++k) {
            float w = wc[k * 2048];
            const float* xk = &xT[k * XS];
            #pragma unroll
            for (int r4 = 0; r4 < TN; r4 += 4) {
                float4 xv = *reinterpret_cast<const float4*>(xk + r4);
                accq[r4 + 0] = fmaf(xv.x, w, accq[r4 + 0]);
                accq[r4 + 1] = fmaf(xv.y, w, accq[r4 + 1]);
                accq[r4 + 2] = fmaf(xv.z, w, accq[r4 + 2]);
                accq[r4 + 3] = fmaf(xv.w, w, accq[r4 + 3]);
            }
        }
        const float bias = bh[h * 256 + tid];
        __syncthreads();   // previous h's down-GEMM reads of qT are done
        #pragma unroll
        for (int r = 0; r < TN; ++r) {
            float pre = __fadd_rn(accq[r], bias);  // chain == Eigen chain bit-for-bit
            lshv[r] += (pre > 0.0f) ? 1 : -1;
            qT[tid * XS + r] = fmaxf(pre, 0.0f);
        }
        __syncthreads();   // qT ready
        const float* wd = Wd + h * 65536 + tid;    // down_kernel[h][k][e=tid], stride 256
        #pragma unroll 2
        for (int k = 0; k < 256; ++k) {
            float w = wd[k * 256];
            const float* qk = &qT[k * XS];
            #pragma unroll
            for (int r4 = 0; r4 < TN; r4 += 4) {
                float4 qv = *reinterpret_cast<const float4*>(qk + r4);
                accz[r4 + 0] = fmaf(qv.x, w, accz[r4 + 0]);
                accz[r4 + 1] = fmaf(qv.y, w, accz[r4 + 1]);
                accz[r4 + 2] = fmaf(qv.z, w, accz[r4 + 2]);
                accz[r4 + 3] = fmaf(qv.w, w, accz[r4 + 3]);
            }
        }
    }
    {
        const float dbias = bd[tid];
        #pragma unroll
        for (int r = 0; r < TN; ++r)
            z[(rowbase + r) * 256 + tid] = fmaxf(accz[r] + dbias, 0.0f);
    }
    __syncthreads();       // last down-GEMM reads of qT / head reads of xT done
    int* lshq = reinterpret_cast<int*>(qT);        // layout [d*33 + r]
    #pragma unroll
    for (int r = 0; r < TN; ++r)
        lshq[tid * 33 + r] = lshv[r];
    __syncthreads();
    if (tid < TN) {
        const int r = tid;
        int* cw = &cnt_l[r * 16];
        for (int i = 0; i < 9; ++i) cw[i] = 0;
        for (int d = 0; d < 256; ++d) {
            int vv = lshq[d * 33 + r];
            cw[(vv + 8) >> 1] += 1;
        }
        // stable counting sort, descending value (argsort(-lsh), jnp stable semantics)
        int run = 0;
        for (int bin = 8; bin >= 0; --bin) { int c0 = cw[bin]; cw[bin] = run; run += c0; }
        float* valq = &xT[r * 256];   // vals in sorted-slot order
        for (int d = 0; d < 256; ++d) {
            int vv = lshq[d * 33 + r];
            int bin = (vv + 8) >> 1;
            int j = cw[bin]++;
            valq[j] = __fadd_rn((float)vv, pe_over[d]);
        }
        // simv: XLA:CPU matrix-vector emitter model:
        // one 8-lane FMA accumulator (lane = slot j mod 8, ascending), then
        // halving shuffle-tree reduce: ((L0+L4)+(L2+L6)) + ((L1+L5)+(L3+L7))
        float L0 = 0.f, L1 = 0.f, L2 = 0.f, L3 = 0.f,
              L4 = 0.f, L5 = 0.f, L6 = 0.f, L7 = 0.f;
        for (int i = 0; i < 256; i += 8) {
            L0 = fmaf(valq[i + 0], c_f[i + 0], L0);
            L1 = fmaf(valq[i + 1], c_f[i + 1], L1);
            L2 = fmaf(valq[i + 2], c_f[i + 2], L2);
            L3 = fmaf(valq[i + 3], c_f[i + 3], L3);
            L4 = fmaf(valq[i + 4], c_f[i + 4], L4);
            L5 = fmaf(valq[i + 5], c_f[i + 5], L5);
            L6 = fmaf(valq[i + 6], c_f[i + 6], L6);
            L7 = fmaf(valq[i + 7], c_f[i + 7], L7);
        }
        const float h0 = __fadd_rn(L0, L4);
        const float h1 = __fadd_rn(L1, L5);
        const float h2 = __fadd_rn(L2, L6);
        const float h3 = __fadd_rn(L3, L7);
        const float g0 = __fadd_rn(h0, h2);
        const float g1 = __fadd_rn(h1, h3);
        simv[rowbase + r] = __fadd_rn(g0, g1);
    }
}

// ---------------- K2: stable rank -> order (argsort of f32 simv per batch) ----------------
__global__ __launch_bounds__(256)
void k2_rank(const float* __restrict__ simv, int* __restrict__ order)
{
    __shared__ float s_l[4096];
    const int b = blockIdx.x >> 4;
    const int chunk = blockIdx.x & 15;
    const float* S = simv + (long)b * 4096;
    for (int i = threadIdx.x; i < 4096; i += 256) s_l[i] = S[i];
    __syncthreads();
    const int n = chunk * 256 + threadIdx.x;
    const float key = s_l[n];
    int cnt = 0;
    for (int m = 0; m < 4096; ++m) {
        float sm = s_l[m];
        cnt += (sm < key) ? 1 : ((sm == key && m < n) ? 1 : 0);
    }
    order[(long)b * 4096 + cnt] = n;
}

// ---------------- K3: value GEMM on gathered (sorted) rows ----------------
__global__ __launch_bounds__(256, 2)
void k3_value(const float* __restrict__ z, const int* __restrict__ order,
              const float* __restrict__ Wv, const float* __restrict__ bv,
              float* __restrict__ v)
{
    __shared__ float zT[256 * XS];
    __shared__ int sh_ord[TN];
    const int tid = threadIdx.x;
    const long rowbase = (long)blockIdx.x * TN;   // global sorted-slot index (b*N+m)
    const long bbase = (rowbase >> 12) << 12;
    if (tid < TN) sh_ord[tid] = order[rowbase + tid];
    __syncthreads();
    #pragma unroll
    for (int r = 0; r < TN; ++r)
        zT[tid * XS + r] = z[(bbase + sh_ord[r]) * 256 + tid];
    float acc[TN];
    #pragma unroll
    for (int r = 0; r < TN; ++r) acc[r] = 0.0f;
    __syncthreads();
    const float* wc = Wv + tid;                   // value_kernel[k][e=tid], stride 256
    #pragma unroll 2
    for (int k = 0; k < 256; ++k) {
        float w = wc[k * 256];
        const float* zk = &zT[k * XS];
        #pragma unroll
        for (int r4 = 0; r4 < TN; r4 += 4) {
            float4 zv = *reinterpret_cast<const float4*>(zk + r4);
            acc[r4 + 0] = fmaf(zv.x, w, acc[r4 + 0]);
            acc[r4 + 1] = fmaf(zv.y, w, acc[r4 + 1]);
            acc[r4 + 2] = fmaf(zv.z, w, acc[r4 + 2]);
            acc[r4 + 3] = fmaf(zv.w, w, acc[r4 + 3]);
        }
    }
    const float bias = bv[tid];
    #pragma unroll
    for (int r = 0; r < TN; ++r)
        v[(rowbase + r) * 256 + tid] = fmaxf(acc[r] + bias, 0.0f);
}

// ---------------- K4: windowed attention + residual + LayerNorm ----------------
__global__ __launch_bounds__(256)
void k4_attn_ln(const float* __restrict__ z, const float* __restrict__ v,
                const int* __restrict__ order, const float* __restrict__ x,
                const float* __restrict__ gamma, const float* __restrict__ beta,
                float* __restrict__ out)
{
    const int tid = threadIdx.x;
    const int wv = tid >> 6, lane = tid & 63;
    const long row = (long)blockIdx.x * 4 + wv;   // output row == sorted slot (b*N+n)
    const int n = (int)(row & 4095);
    const long bbase = row - n;
    int start = n - 4;
    start = start < 0 ? 0 : start;
    start = start > (Nc - 9) ? (Nc - 9) : start;
    const int d0 = lane * 4;

    const int srcq = order[bbase + n];
    float4 q4 = *reinterpret_cast<const float4*>(&z[(bbase + srcq) * 256 + d0]);

    float t[9];
    #pragma unroll
    for (int w = 0; w < 9; ++w) {
        int srcm = order[bbase + start + w];
        float4 kv = *reinterpret_cast<const float4*>(&z[(bbase + srcm) * 256 + d0]);
        float p = q4.x * kv.x + q4.y * kv.y + q4.z * kv.z + q4.w * kv.w;
        #pragma unroll
        for (int off = 32; off > 0; off >>= 1) p += __shfl_xor(p, off);
        t[w] = p * 0.0625f;   // / sqrt(256)
    }
    float mx = t[0];
    #pragma unroll
    for (int w = 1; w < 9; ++w) mx = fmaxf(mx, t[w]);
    float pw[9], psum = 0.0f;
    #pragma unroll
    for (int w = 0; w < 9; ++w) { pw[w] = expf(t[w] - mx); psum += pw[w]; }
    const float pinv = 1.0f / psum;

    float4 a = make_float4(0.f, 0.f, 0.f, 0.f);
    #pragma unroll
    for (int w = 0; w < 9; ++w) {
        float4 vv = *reinterpret_cast<const float4*>(&v[(bbase + start + w) * 256 + d0]);
        float s = pw[w] * pinv;
        a.x = fmaf(vv.x, s, a.x);
        a.y = fmaf(vv.y, s, a.y);
        a.z = fmaf(vv.z, s, a.z);
        a.w = fmaf(vv.w, s, a.w);
    }
    float4 xv = *reinterpret_cast<const float4*>(&x[(bbase + n) * 256 + d0]);
    float4 y = make_float4(a.x + xv.x, a.y + xv.y, a.z + xv.z, a.w + xv.w);

    float s1 = y.x + y.y + y.z + y.w;
    float s2 = y.x * y.x + y.y * y.y + y.z * y.z + y.w * y.w;
    #pragma unroll
    for (int off = 32; off > 0; off >>= 1) {
        s1 += __shfl_xor(s1, off);
        s2 += __shfl_xor(s2, off);
    }
    const float mu = s1 * (1.0f / 256.0f);
    const float var = s2 * (1.0f / 256.0f) - mu * mu;
    const float istd = 1.0f / sqrtf(var + 0.001f);

    float4 g4 = *reinterpret_cast<const float4*>(&gamma[d0]);
    float4 b4 = *reinterpret_cast<const float4*>(&beta[d0]);
    float4 o;
    o.x = (y.x - mu) * istd * g4.x + b4.x;
    o.y = (y.y - mu) * istd * g4.y + b4.y;
    o.z = (y.z - mu) * istd * g4.z + b4.z;
    o.w = (y.w - mu) * istd * g4.w + b4.w;
    *reinterpret_cast<float4*>(&out[row * 256 + d0]) = o;
}

extern "C" void kernel_launch(void* const* d_in, const int* in_sizes, int n_in,
                              void* d_out, int out_size, void* d_ws, size_t ws_size,
                              hipStream_t stream)
{
    const float* x  = (const float*)d_in[0];
    const float* Wh = (const float*)d_in[1];
    const float* bh = (const float*)d_in[2];
    const float* Wd = (const float*)d_in[3];
    const float* bd = (const float*)d_in[4];
    const float* Wv = (const float*)d_in[5];
    const float* bv = (const float*)d_in[6];
    const float* g  = (const float*)d_in[7];
    const float* be = (const float*)d_in[8];
    float* out = (float*)d_out;

    char* ws = (char*)d_ws;
    float* z     = (float*)ws;                       // 33554432 B
    float* v     = (float*)(ws + 33554432);          // 33554432 B
    float* simv  = (float*)(ws + 67108864);          // 131072 B
    int*   order = (int*)(ws + 67239936);            // 131072 B

    const int rows = Bc * Nc;                        // 32768
    k1_head_down<<<dim3(rows / TN), dim3(256), 0, stream>>>(x, Wh, bh, Wd, bd, z, simv);
    k2_rank<<<dim3(Bc * 16), dim3(256), 0, stream>>>(simv, order);
    k3_value<<<dim3(rows / TN), dim3(256), 0, stream>>>(z, order, Wv, bv, v);
    k4_attn_ln<<<dim3(rows / 4), dim3(256), 0, stream>>>(z, v, order, x, g, be, out);
}

// Round 10
// 926.223 us; speedup vs baseline: 1.8359x; 1.8359x over previous
//
#include <hip/hip_runtime.h>

constexpr int Bc = 8, Nc = 4096, Dc = 256, Hc = 8;
constexpr int TN = 16;    // rows per workgroup in K1
constexpr int XS = 20;    // xT padded stride (16 rows + 4 pad, 16B-aligned)
constexpr int TN3 = 32;   // rows per workgroup in K3
constexpr int XS3 = 36;

using short8 = __attribute__((ext_vector_type(8))) short;
using f32x4  = __attribute__((ext_vector_type(4))) float;

static __device__ __forceinline__ unsigned short f2bf(float f) {
    unsigned u = __float_as_uint(f);
    u += 0x7fffu + ((u >> 16) & 1u);     // RNE
    return (unsigned short)(u >> 16);
}

// ---------------- K0: Wd [h][d][e] f32 -> WdT [h][e][d] bf16 (one-time, 1 MB) ----------------
__global__ __launch_bounds__(256)
void k0_wdt(const float* __restrict__ Wd, unsigned short* __restrict__ WdT)
{
    __shared__ float tile[64][65];
    const int h  = blockIdx.x >> 4;
    const int t  = blockIdx.x & 15;
    const int kb = (t >> 2) * 64, eb = (t & 3) * 64;
    const int tid = threadIdx.x;
    {
        const int krow = tid >> 2, ec = (tid & 3) * 16;
        const float* src = Wd + h * 65536 + (kb + krow) * 256 + eb + ec;
        #pragma unroll
        for (int i = 0; i < 4; ++i) {
            float4 v = *reinterpret_cast<const float4*>(src + i * 4);
            tile[krow][ec + i * 4 + 0] = v.x;
            tile[krow][ec + i * 4 + 1] = v.y;
            tile[krow][ec + i * 4 + 2] = v.z;
            tile[krow][ec + i * 4 + 3] = v.w;
        }
    }
    __syncthreads();
    {
        const int erow = tid >> 2, dc = (tid & 3) * 16;
        unsigned short o[16];
        #pragma unroll
        for (int i = 0; i < 16; ++i) o[i] = f2bf(tile[dc + i][erow]);
        unsigned short* dst = WdT + h * 65536 + (eb + erow) * 256 + kb + dc;
        *reinterpret_cast<short8*>(dst)     = *reinterpret_cast<short8*>(&o[0]);
        *reinterpret_cast<short8*>(dst + 8) = *reinterpret_cast<short8*>(&o[8]);
    }
}

// ---------------- K1: head GEMM (exact f32 chain) + MFMA down GEMM + lsh/simv ----------------
__global__ __launch_bounds__(256, 4)
void k1_head_down(const float* __restrict__ x,
                  const float* __restrict__ Wh, const float* __restrict__ bh,
                  const unsigned short* __restrict__ WdT, const float* __restrict__ bd,
                  float* __restrict__ z, float* __restrict__ simv)
{
    __shared__ float xT[256 * XS];            // [k][r] padded; reused as valq scratch in tail
    __shared__ unsigned short qTb[TN * 256];  // per-h q tile, bf16 [r][d]
    __shared__ signed char lshL[256 * 17];    // lsh per (e=tid, r)
    __shared__ float pe_over[256];
    __shared__ float c_f[256];
    __shared__ int   cnt_l[TN * 16];

    const int tid = threadIdx.x;
    const long rowbase = (long)blockIdx.x * TN;

    {
        // XLA:CPU twin tables: llvm.pow/sin/cos.f32 -> glibc CR -> f64-compute-then-round
        const int d = tid;
        const float u = -((float)d * 0.00390625f);
        const float freq = (float)pow(10.0, (double)u);
        const float pe = (d & 1) ? (float)sin((double)freq)
                                 : (float)cos((double)freq);
        pe_over[d] = __fdiv_rn(pe, 0.4f);
        c_f[d] = __fmul_rn(0.4f, (float)pow((double)0.6f, (double)d));
    }
    #pragma unroll
    for (int r = 0; r < TN; ++r)
        xT[tid * XS + r] = x[(rowbase + r) * 256 + tid];

    int lshv[TN];
    #pragma unroll
    for (int r = 0; r < TN; ++r) lshv[r] = 0;

    const int wavei = tid >> 6, lane = tid & 63;
    const int mrow = lane & 15, kgrp = lane >> 4;
    f32x4 acc[4];
    #pragma unroll
    for (int nf = 0; nf < 4; ++nf) acc[nf] = (f32x4){0.f, 0.f, 0.f, 0.f};

    __syncthreads();

    for (int h = 0; h < Hc; ++h) {
        // ---- phase 1: head GEMM, exact ascending-k f32 FMA chain (Eigen twin) ----
        float accq[TN];
        #pragma unroll
        for (int r = 0; r < TN; ++r) accq[r] = 0.0f;
        const float* wcol = Wh + h * 256 + tid;        // stride 2048
        float wb[8];
        #pragma unroll
        for (int i = 0; i < 8; ++i) wb[i] = wcol[i * 2048];
        for (int k0 = 0; k0 < 256; k0 += 8) {
            float wn[8];
            const bool more = (k0 + 8) < 256;
            if (more) {
                #pragma unroll
                for (int i = 0; i < 8; ++i) wn[i] = wcol[(k0 + 8 + i) * 2048];
            }
            #pragma unroll
            for (int i = 0; i < 8; ++i) {
                const float* xk = &xT[(k0 + i) * XS];
                const float w = wb[i];
                #pragma unroll
                for (int r4 = 0; r4 < TN; r4 += 4) {
                    float4 xv = *reinterpret_cast<const float4*>(xk + r4);
                    accq[r4 + 0] = fmaf(xv.x, w, accq[r4 + 0]);
                    accq[r4 + 1] = fmaf(xv.y, w, accq[r4 + 1]);
                    accq[r4 + 2] = fmaf(xv.z, w, accq[r4 + 2]);
                    accq[r4 + 3] = fmaf(xv.w, w, accq[r4 + 3]);
                }
            }
            if (more) {
                #pragma unroll
                for (int i = 0; i < 8; ++i) wb[i] = wn[i];
            }
        }
        const float bias = bh[h * 256 + tid];
        __syncthreads();   // previous h's mfma reads of qTb complete
        #pragma unroll
        for (int r = 0; r < TN; ++r) {
            const float pre = __fadd_rn(accq[r], bias);   // sign == XLA-CPU bit-for-bit
            lshv[r] += (pre > 0.0f) ? 1 : -1;
            qTb[r * 256 + tid] = f2bf(fmaxf(pre, 0.0f));
        }
        __syncthreads();   // qTb ready
        // ---- phase 2: down GEMM via MFMA (continuous path, bf16 ok) ----
        const unsigned short* wdh = WdT + h * 65536;
        #pragma unroll 2
        for (int ks = 0; ks < 8; ++ks) {
            short8 af = *reinterpret_cast<const short8*>(&qTb[mrow * 256 + ks * 32 + kgrp * 8]);
            #pragma unroll
            for (int nf = 0; nf < 4; ++nf) {
                const int e = wavei * 64 + nf * 16 + mrow;
                short8 bf = *reinterpret_cast<const short8*>(&wdh[e * 256 + ks * 32 + kgrp * 8]);
                acc[nf] = __builtin_amdgcn_mfma_f32_16x16x32_bf16(af, bf, acc[nf], 0, 0, 0);
            }
        }
    }
    // ---- epilogue: z = relu(acc + bd) ----
    #pragma unroll
    for (int nf = 0; nf < 4; ++nf) {
        const int e = wavei * 64 + nf * 16 + mrow;
        const float b = bd[e];
        #pragma unroll
        for (int reg = 0; reg < 4; ++reg) {
            const int m = kgrp * 4 + reg;     // D row = (lane>>4)*4 + reg
            z[(rowbase + m) * 256 + e] = fmaxf(acc[nf][reg] + b, 0.0f);
        }
    }
    // ---- lsh export + simv tail (bit-exact path, unchanged semantics) ----
    #pragma unroll
    for (int r = 0; r < TN; ++r)
        lshL[tid * 17 + r] = (signed char)lshv[r];
    __syncthreads();
    if (tid < TN) {
        const int r = tid;
        int* cw = &cnt_l[r * 16];
        for (int i = 0; i < 9; ++i) cw[i] = 0;
        for (int d = 0; d < 256; ++d) {
            int vv = (int)lshL[d * 17 + r];
            cw[(vv + 8) >> 1] += 1;
        }
        int run = 0;
        for (int bin = 8; bin >= 0; --bin) { int c0 = cw[bin]; cw[bin] = run; run += c0; }
        float* valq = &xT[r * 256];
        for (int d = 0; d < 256; ++d) {
            int vv = (int)lshL[d * 17 + r];
            int bin = (vv + 8) >> 1;
            int j = cw[bin]++;
            valq[j] = __fadd_rn((float)vv, pe_over[d]);
        }
        // XLA:CPU matrix-vector emitter: 8-lane FMA accum + halving tree
        float L0 = 0.f, L1 = 0.f, L2 = 0.f, L3 = 0.f,
              L4 = 0.f, L5 = 0.f, L6 = 0.f, L7 = 0.f;
        for (int i = 0; i < 256; i += 8) {
            L0 = fmaf(valq[i + 0], c_f[i + 0], L0);
            L1 = fmaf(valq[i + 1], c_f[i + 1], L1);
            L2 = fmaf(valq[i + 2], c_f[i + 2], L2);
            L3 = fmaf(valq[i + 3], c_f[i + 3], L3);
            L4 = fmaf(valq[i + 4], c_f[i + 4], L4);
            L5 = fmaf(valq[i + 5], c_f[i + 5], L5);
            L6 = fmaf(valq[i + 6], c_f[i + 6], L6);
            L7 = fmaf(valq[i + 7], c_f[i + 7], L7);
        }
        const float h0 = __fadd_rn(L0, L4);
        const float h1 = __fadd_rn(L1, L5);
        const float h2 = __fadd_rn(L2, L6);
        const float h3 = __fadd_rn(L3, L7);
        simv[rowbase + r] = __fadd_rn(__fadd_rn(h0, h2), __fadd_rn(h1, h3));
    }
}

// ---------------- K2: stable rank -> order (argsort of f32 simv per batch) ----------------
__global__ __launch_bounds__(256)
void k2_rank(const float* __restrict__ simv, int* __restrict__ order)
{
    __shared__ float s_l[4096];
    const int b = blockIdx.x >> 4;
    const int chunk = blockIdx.x & 15;
    const float* S = simv + (long)b * 4096;
    for (int i = threadIdx.x; i < 4096; i += 256) s_l[i] = S[i];
    __syncthreads();
    const int n = chunk * 256 + threadIdx.x;
    const float key = s_l[n];
    int cnt = 0;
    for (int m = 0; m < 4096; ++m) {
        float sm = s_l[m];
        cnt += (sm < key) ? 1 : ((sm == key && m < n) ? 1 : 0);
    }
    order[(long)b * 4096 + cnt] = n;
}

// ---------------- K3: value GEMM on gathered (sorted) rows ----------------
__global__ __launch_bounds__(256, 2)
void k3_value(const float* __restrict__ z, const int* __restrict__ order,
              const float* __restrict__ Wv, const float* __restrict__ bv,
              float* __restrict__ v)
{
    __shared__ float zT[256 * XS3];
    __shared__ int sh_ord[TN3];
    const int tid = threadIdx.x;
    const long rowbase = (long)blockIdx.x * TN3;
    const long bbase = (rowbase >> 12) << 12;
    if (tid < TN3) sh_ord[tid] = order[rowbase + tid];
    __syncthreads();
    #pragma unroll
    for (int r = 0; r < TN3; ++r)
        zT[tid * XS3 + r] = z[(bbase + sh_ord[r]) * 256 + tid];
    float acc[TN3];
    #pragma unroll
    for (int r = 0; r < TN3; ++r) acc[r] = 0.0f;
    __syncthreads();
    const float* wc = Wv + tid;
    #pragma unroll 2
    for (int k = 0; k < 256; ++k) {
        float w = wc[k * 256];
        const float* zk = &zT[k * XS3];
        #pragma unroll
        for (int r4 = 0; r4 < TN3; r4 += 4) {
            float4 zv = *reinterpret_cast<const float4*>(zk + r4);
            acc[r4 + 0] = fmaf(zv.x, w, acc[r4 + 0]);
            acc[r4 + 1] = fmaf(zv.y, w, acc[r4 + 1]);
            acc[r4 + 2] = fmaf(zv.z, w, acc[r4 + 2]);
            acc[r4 + 3] = fmaf(zv.w, w, acc[r4 + 3]);
        }
    }
    const float bias = bv[tid];
    #pragma unroll
    for (int r = 0; r < TN3; ++r)
        v[(rowbase + r) * 256 + tid] = fmaxf(acc[r] + bias, 0.0f);
}

// ---------------- K4: windowed attention + residual + LayerNorm ----------------
__global__ __launch_bounds__(256)
void k4_attn_ln(const float* __restrict__ z, const float* __restrict__ v,
                const int* __restrict__ order, const float* __restrict__ x,
                const float* __restrict__ gamma, const float* __restrict__ beta,
                float* __restrict__ out)
{
    const int tid = threadIdx.x;
    const int wv = tid >> 6, lane = tid & 63;
    const long row = (long)blockIdx.x * 4 + wv;
    const int n = (int)(row & 4095);
    const long bbase = row - n;
    int start = n - 4;
    start = start < 0 ? 0 : start;
    start = start > (Nc - 9) ? (Nc - 9) : start;
    const int d0 = lane * 4;

    const int srcq = order[bbase + n];
    float4 q4 = *reinterpret_cast<const float4*>(&z[(bbase + srcq) * 256 + d0]);

    float t[9];
    #pragma unroll
    for (int w = 0; w < 9; ++w) {
        int srcm = order[bbase + start + w];
        float4 kv = *reinterpret_cast<const float4*>(&z[(bbase + srcm) * 256 + d0]);
        float p = q4.x * kv.x + q4.y * kv.y + q4.z * kv.z + q4.w * kv.w;
        #pragma unroll
        for (int off = 32; off > 0; off >>= 1) p += __shfl_xor(p, off);
        t[w] = p * 0.0625f;
    }
    float mx = t[0];
    #pragma unroll
    for (int w = 1; w < 9; ++w) mx = fmaxf(mx, t[w]);
    float pw[9], psum = 0.0f;
    #pragma unroll
    for (int w = 0; w < 9; ++w) { pw[w] = expf(t[w] - mx); psum += pw[w]; }
    const float pinv = 1.0f / psum;

    float4 a = make_float4(0.f, 0.f, 0.f, 0.f);
    #pragma unroll
    for (int w = 0; w < 9; ++w) {
        float4 vv = *reinterpret_cast<const float4*>(&v[(bbase + start + w) * 256 + d0]);
        float s = pw[w] * pinv;
        a.x = fmaf(vv.x, s, a.x);
        a.y = fmaf(vv.y, s, a.y);
        a.z = fmaf(vv.z, s, a.z);
        a.w = fmaf(vv.w, s, a.w);
    }
    float4 xv = *reinterpret_cast<const float4*>(&x[(bbase + n) * 256 + d0]);
    float4 y = make_float4(a.x + xv.x, a.y + xv.y, a.z + xv.z, a.w + xv.w);

    float s1 = y.x + y.y + y.z + y.w;
    float s2 = y.x * y.x + y.y * y.y + y.z * y.z + y.w * y.w;
    #pragma unroll
    for (int off = 32; off > 0; off >>= 1) {
        s1 += __shfl_xor(s1, off);
        s2 += __shfl_xor(s2, off);
    }
    const float mu = s1 * (1.0f / 256.0f);
    const float var = s2 * (1.0f / 256.0f) - mu * mu;
    const float istd = 1.0f / sqrtf(var + 0.001f);

    float4 g4 = *reinterpret_cast<const float4*>(&gamma[d0]);
    float4 b4 = *reinterpret_cast<const float4*>(&beta[d0]);
    float4 o;
    o.x = (y.x - mu) * istd * g4.x + b4.x;
    o.y = (y.y - mu) * istd * g4.y + b4.y;
    o.z = (y.z - mu) * istd * g4.z + b4.z;
    o.w = (y.w - mu) * istd * g4.w + b4.w;
    *reinterpret_cast<float4*>(&out[row * 256 + d0]) = o;
}

extern "C" void kernel_launch(void* const* d_in, const int* in_sizes, int n_in,
                              void* d_out, int out_size, void* d_ws, size_t ws_size,
                              hipStream_t stream)
{
    const float* x  = (const float*)d_in[0];
    const float* Wh = (const float*)d_in[1];
    const float* bh = (const float*)d_in[2];
    const float* Wd = (const float*)d_in[3];
    const float* bd = (const float*)d_in[4];
    const float* Wv = (const float*)d_in[5];
    const float* bv = (const float*)d_in[6];
    const float* g  = (const float*)d_in[7];
    const float* be = (const float*)d_in[8];
    float* out = (float*)d_out;

    char* ws = (char*)d_ws;
    float*          z     = (float*)ws;                      // 33554432 B
    float*          v     = (float*)(ws + 33554432);         // 33554432 B
    float*          simv  = (float*)(ws + 67108864);         // 131072 B
    int*            order = (int*)(ws + 67239936);           // 131072 B
    unsigned short* WdT   = (unsigned short*)(ws + 67371008);// 1048576 B

    const int rows = Bc * Nc;                                // 32768
    k0_wdt<<<dim3(128), dim3(256), 0, stream>>>(Wd, WdT);
    k1_head_down<<<dim3(rows / TN), dim3(256), 0, stream>>>(x, Wh, bh, WdT, bd, z, simv);
    k2_rank<<<dim3(Bc * 16), dim3(256), 0, stream>>>(simv, order);
    k3_value<<<dim3(rows / TN3), dim3(256), 0, stream>>>(z, order, Wv, bv, v);
    k4_attn_ln<<<dim3(rows / 4), dim3(256), 0, stream>>>(z, v, order, x, g, be, out);
}